// Round 1
// baseline (323.312 us; speedup 1.0000x reference)
//
#include <hip/hip_runtime.h>
#include <hip/hip_bf16.h>
#include <math.h>

// MultiHeadSelfAttention: B=2,S=2048,D=1024,H=16,hd=64, fp32 in/out.
// Strategy: bf16 MFMA (fp32 accum) for all GEMMs; flash attention with
// in-register online softmax. Threshold is 1.47e-3 abs (2% of ref absmax);
// bf16-input/fp32-accum error lands ~1e-4 (K=1024 accumulation noise washes
// out: proj inputs are small, attention averages q/k/v rounding noise).

typedef __bf16 bf16_t;
typedef __bf16 bf16x8 __attribute__((ext_vector_type(8)));
typedef __bf16 bf16x4v __attribute__((ext_vector_type(4)));
typedef float f32x4 __attribute__((ext_vector_type(4)));

#define B_ 2
#define S_ 2048
#define D_ 1024
#define H_ 16
#define HD_ 64
// fold softmax scale (1/8) * log2(e) into Q so scores feed exp2 directly
#define QSCALE 0.18033688011112042f

__device__ __forceinline__ void load_lds16(const void* g, void* s) {
  // direct global->LDS DMA, 16B/lane; LDS dest is wave-uniform base + lane*16
  __builtin_amdgcn_global_load_lds((__attribute__((address_space(1))) unsigned int*)g,
                                   (__attribute__((address_space(3))) unsigned int*)s,
                                   16, 0, 0);
}

__device__ __forceinline__ float red_max16(float v) {
  v = fmaxf(v, __shfl_xor(v, 1));
  v = fmaxf(v, __shfl_xor(v, 2));
  v = fmaxf(v, __shfl_xor(v, 4));
  v = fmaxf(v, __shfl_xor(v, 8));
  return v;
}
__device__ __forceinline__ float red_sum16(float v) {
  v += __shfl_xor(v, 1);
  v += __shfl_xor(v, 2);
  v += __shfl_xor(v, 4);
  v += __shfl_xor(v, 8);
  return v;
}

// ---------------- fp32 -> bf16 convert (vectorized) ----------------
__global__ void tobf16(const float* __restrict__ in, bf16_t* __restrict__ out, int n4) {
  int i = blockIdx.x * 256 + threadIdx.x;
  if (i >= n4) return;
  float4 v = ((const float4*)in)[i];
  bf16x4v o;
  o[0] = (bf16_t)v.x; o[1] = (bf16_t)v.y; o[2] = (bf16_t)v.z; o[3] = (bf16_t)v.w;
  ((bf16x4v*)out)[i] = o;
}

// ---------------- GEMM: C[M,N] = A[M,K] @ B[N,K]^T + bias ----------------
// 128x128 tile, BK=32, 256 threads (4 waves 2x2), m97-style global_load_lds.
// EPI=0: QKV epilogue (scatter to q/k/vT bf16 layouts, q pre-scaled)
// EPI=1: proj epilogue (fp32 out)
template <int EPI>
__global__ __launch_bounds__(256, 2) void gemm_bt(
    const bf16_t* __restrict__ A, const bf16_t* __restrict__ Bm,
    const float* __restrict__ bias,
    bf16_t* __restrict__ qb, bf16_t* __restrict__ kb, bf16_t* __restrict__ vtb,
    float* __restrict__ outf) {
  __shared__ __align__(16) bf16_t sA[128 * 32];
  __shared__ __align__(16) bf16_t sB[128 * 32];
  const int tid = threadIdx.x;
  const int w = tid >> 6, lane = tid & 63;
  const int wm = w >> 1, wn = w & 1;
  const int quad = lane >> 4, l15 = lane & 15;
  const int m0 = blockIdx.y * 128, n0 = blockIdx.x * 128;

  f32x4 acc[4][4];
#pragma unroll
  for (int mi = 0; mi < 4; mi++)
#pragma unroll
    for (int ni = 0; ni < 4; ni++) acc[mi][ni] = (f32x4){0.f, 0.f, 0.f, 0.f};

  for (int kt = 0; kt < 1024; kt += 32) {
    __syncthreads();  // prior LDS reads done before restage
#pragma unroll
    for (int i = 0; i < 2; i++) {
      int ub = w * 128 + i * 64;
      int u = ub + lane;
      load_lds16(A + (size_t)(m0 + (u >> 2)) * 1024 + kt + (u & 3) * 8, sA + ub * 8);
      load_lds16(Bm + (size_t)(n0 + (u >> 2)) * 1024 + kt + (u & 3) * 8, sB + ub * 8);
    }
    __syncthreads();  // drains vmcnt -> staged data visible
    bf16x8 af[4], bfr[4];
#pragma unroll
    for (int mi = 0; mi < 4; mi++)
      af[mi] = *(const bf16x8*)(sA + (wm * 64 + mi * 16 + l15) * 32 + quad * 8);
#pragma unroll
    for (int ni = 0; ni < 4; ni++)
      bfr[ni] = *(const bf16x8*)(sB + (wn * 64 + ni * 16 + l15) * 32 + quad * 8);
#pragma unroll
    for (int mi = 0; mi < 4; mi++)
#pragma unroll
      for (int ni = 0; ni < 4; ni++)
        acc[mi][ni] = __builtin_amdgcn_mfma_f32_16x16x32_bf16(af[mi], bfr[ni], acc[mi][ni], 0, 0, 0);
  }

  // epilogue: C row = m0+wm*64+mi*16+quad*4+r, col = n0+wn*64+ni*16+l15
#pragma unroll
  for (int mi = 0; mi < 4; mi++) {
#pragma unroll
    for (int ni = 0; ni < 4; ni++) {
      int n = n0 + wn * 64 + ni * 16 + l15;
      float bv = bias[n];
#pragma unroll
      for (int r = 0; r < 4; r++) {
        int m = m0 + wm * 64 + mi * 16 + quad * 4 + r;
        float v = acc[mi][ni][r] + bv;
        if (EPI == 0) {
          int t = n >> 10;           // 0=Q,1=K,2=V (uniform per block: 128 | 1024)
          int rr = n & 1023;
          int hh = rr >> 6, d = rr & 63;
          int bb = m >> 11, s = m & 2047;
          size_t bh = (size_t)(bb * H_ + hh);
          if (t == 0)
            qb[(bh * S_ + s) * HD_ + d] = (bf16_t)(v * QSCALE);
          else if (t == 1)
            kb[(bh * S_ + s) * HD_ + d] = (bf16_t)v;
          else
            vtb[(bh * HD_ + d) * S_ + s] = (bf16_t)v;  // V transposed for PV B-operand
        } else {
          outf[(size_t)m * 1024 + n] = v;
        }
      }
    }
  }
}

// ---------------- flash attention ----------------
// block = one (b,h,q-tile of 64). 4 waves; wave w owns q rows w*16..w*16+15
// for BOTH QK^T and PV -> online-softmax state (m,l,alpha) lives in registers.
// kv-tile = 128. P transits LDS (C-layout -> A-layout), stride 136 (272B, 16B-mult).
__global__ __launch_bounds__(256, 2) void attn(
    const bf16_t* __restrict__ qb, const bf16_t* __restrict__ kb,
    const bf16_t* __restrict__ vtb, bf16_t* __restrict__ ob) {
  __shared__ __align__(16) bf16_t sQ[64 * 64];    // 8 KB
  __shared__ __align__(16) bf16_t sK[128 * 64];   // 16 KB
  __shared__ __align__(16) bf16_t sV[64 * 128];   // 16 KB  [d][s]
  __shared__ __align__(16) bf16_t sP[64 * 136];   // 17 KB  (pad 8 -> 272B rows)
  const int tid = threadIdx.x, w = tid >> 6, lane = tid & 63;
  const int quad = lane >> 4, l15 = lane & 15;
  const int qt = blockIdx.x, bh = blockIdx.y;
  const int b = bh >> 4, h = bh & 15;
  const size_t base = (size_t)bh * S_ * HD_;
  const int q0 = qt * 64;

  // stage Q tile (contiguous 8KB): 512x16B units, 2 per lane
#pragma unroll
  for (int i = 0; i < 2; i++) {
    int ub = w * 128 + i * 64;
    load_lds16(qb + base + (size_t)q0 * HD_ + (size_t)(ub + lane) * 8, sQ + ub * 8);
  }

  f32x4 acc_o[4];
#pragma unroll
  for (int ni = 0; ni < 4; ni++) acc_o[ni] = (f32x4){0.f, 0.f, 0.f, 0.f};
  float m_r[4], l_r[4];
#pragma unroll
  for (int r = 0; r < 4; r++) { m_r[r] = -3.0e38f; l_r[r] = 0.f; }

  for (int j = 0; j < 16; j++) {
    const int kv0 = j * 128;
    __syncthreads();  // prev iter's K/V reads done (also drains Q stage on j=0)
    // stage K tile (contiguous 16KB) and V^T tile ([64][128], rows stride S_)
#pragma unroll
    for (int i = 0; i < 4; i++) {
      int ub = w * 256 + i * 64;
      int u = ub + lane;
      load_lds16(kb + base + (size_t)kv0 * HD_ + (size_t)u * 8, sK + ub * 8);
      load_lds16(vtb + (size_t)bh * HD_ * S_ + (size_t)(u >> 4) * S_ + kv0 + (u & 15) * 8,
                 sV + ub * 8);
    }
    __syncthreads();

    // S = Q K^T : wave w -> rows w*16.., all 128 kv cols (8 n-tiles, 2 k-steps)
    f32x4 s_acc[8];
#pragma unroll
    for (int ni = 0; ni < 8; ni++) s_acc[ni] = (f32x4){0.f, 0.f, 0.f, 0.f};
#pragma unroll
    for (int kk = 0; kk < 2; kk++) {
      bf16x8 aq = *(const bf16x8*)(sQ + (w * 16 + l15) * 64 + kk * 32 + quad * 8);
#pragma unroll
      for (int ni = 0; ni < 8; ni++) {
        bf16x8 bk = *(const bf16x8*)(sK + (ni * 16 + l15) * 64 + kk * 32 + quad * 8);
        s_acc[ni] = __builtin_amdgcn_mfma_f32_16x16x32_bf16(aq, bk, s_acc[ni], 0, 0, 0);
      }
    }

    // online softmax (base-2; scale folded into Q). Row = w*16+quad*4+r.
    float alpha[4];
#pragma unroll
    for (int r = 0; r < 4; r++) {
      float mx = s_acc[0][r];
#pragma unroll
      for (int ni = 1; ni < 8; ni++) mx = fmaxf(mx, s_acc[ni][r]);
      mx = red_max16(mx);
      float mn = fmaxf(m_r[r], mx);
      alpha[r] = exp2f(m_r[r] - mn);  // first iter: exp2(-3e38)=0
      m_r[r] = mn;
      float rs = 0.f;
#pragma unroll
      for (int ni = 0; ni < 8; ni++) {
        float p = exp2f(s_acc[ni][r] - mn);
        rs += p;
        sP[(w * 16 + quad * 4 + r) * 136 + ni * 16 + l15] = (bf16_t)p;
      }
      rs = red_sum16(rs);
      l_r[r] = l_r[r] * alpha[r] + rs;
    }
    // no barrier: wave w writes AND reads only P rows w*16..w*16+15 (in-order LDS)

#pragma unroll
    for (int ni = 0; ni < 4; ni++)
#pragma unroll
      for (int r = 0; r < 4; r++) acc_o[ni][r] *= alpha[r];

    // O += P @ V : A = P rows (A-layout from LDS), B = V^T [d][s]
#pragma unroll
    for (int ks = 0; ks < 4; ks++) {
      bf16x8 ap = *(const bf16x8*)(sP + (w * 16 + l15) * 136 + ks * 32 + quad * 8);
#pragma unroll
      for (int ni = 0; ni < 4; ni++) {
        bf16x8 bv = *(const bf16x8*)(sV + (ni * 16 + l15) * 128 + ks * 32 + quad * 8);
        acc_o[ni] = __builtin_amdgcn_mfma_f32_16x16x32_bf16(ap, bv, acc_o[ni], 0, 0, 0);
      }
    }
  }

  // epilogue: O row q, col d; write bf16 to [B,S,D] for proj GEMM
#pragma unroll
  for (int ni = 0; ni < 4; ni++)
#pragma unroll
    for (int r = 0; r < 4; r++) {
      int q = q0 + w * 16 + quad * 4 + r;
      int d = ni * 16 + l15;
      float v = acc_o[ni][r] / l_r[r];
      ob[((size_t)b * S_ + q) * D_ + h * HD_ + d] = (bf16_t)v;
    }
}

// ---------------- launcher ----------------
extern "C" void kernel_launch(void* const* d_in, const int* in_sizes, int n_in,
                              void* d_out, int out_size, void* d_ws, size_t ws_size,
                              hipStream_t stream) {
  const float* x = (const float*)d_in[0];        // [2,2048,1024]
  const float* w_qkv = (const float*)d_in[1];    // [3072,1024]
  const float* b_qkv = (const float*)d_in[2];    // [3072]
  const float* w_proj = (const float*)d_in[3];   // [1024,1024]
  const float* b_proj = (const float*)d_in[4];   // [1024]
  float* out = (float*)d_out;

  char* ws = (char*)d_ws;
  size_t off = 0;
  bf16_t* xb = (bf16_t*)(ws + off); off += (size_t)4096 * 1024 * 2;    // 8 MB
  bf16_t* wqkvb = (bf16_t*)(ws + off); off += (size_t)3072 * 1024 * 2; // 6 MB
  bf16_t* wpb = (bf16_t*)(ws + off); off += (size_t)1024 * 1024 * 2;   // 2 MB
  bf16_t* qb = (bf16_t*)(ws + off); off += (size_t)4096 * 1024 * 2;    // 8 MB [B,H,S,hd]
  bf16_t* kb = (bf16_t*)(ws + off); off += (size_t)4096 * 1024 * 2;    // 8 MB [B,H,S,hd]
  bf16_t* vtb = (bf16_t*)(ws + off); off += (size_t)4096 * 1024 * 2;   // 8 MB [B,H,hd,S]
  bf16_t* ob = xb;  // xb dead after QKV GEMM; reuse for attention output
  // total ws use: 41,943,040 B

  tobf16<<<4096, 256, 0, stream>>>(x, xb, 1048576);
  tobf16<<<3072, 256, 0, stream>>>(w_qkv, wqkvb, 786432);
  tobf16<<<1024, 256, 0, stream>>>(w_proj, wpb, 262144);
  gemm_bt<0><<<dim3(24, 32), 256, 0, stream>>>(xb, wqkvb, b_qkv, qb, kb, vtb, nullptr);
  attn<<<dim3(32, 32), 256, 0, stream>>>(qb, kb, vtb, ob);
  gemm_bt<1><<<dim3(8, 32), 256, 0, stream>>>(ob, wpb, b_proj, nullptr, nullptr, nullptr, out);
}

// Round 2
// 265.828 us; speedup vs baseline: 1.2162x; 1.2162x over previous
//
#include <hip/hip_runtime.h>
#include <hip/hip_bf16.h>
#include <math.h>

// MultiHeadSelfAttention: B=2,S=2048,D=1024,H=16,hd=64, fp32 in/out.
// bf16 MFMA everywhere; flash attention with in-register online softmax.
// R2: XOR-swizzled LDS (kills 8/16-way ds_read_b128 bank conflicts, which were
// ~40% of attn cycles in R1), Q held in registers (LDS 58->50 KB => 3 blk/CU),
// proj GEMM retiled 128x64 (512 blocks instead of 256 == 1/CU).

typedef __bf16 bf16_t;
typedef __bf16 bf16x8 __attribute__((ext_vector_type(8)));
typedef __bf16 bf16x4v __attribute__((ext_vector_type(4)));
typedef float f32x4 __attribute__((ext_vector_type(4)));

#define B_ 2
#define S_ 2048
#define D_ 1024
#define H_ 16
#define HD_ 64
// fold softmax scale (1/8) * log2(e) into Q so scores feed exp2 directly
#define QSCALE 0.18033688011112042f

__device__ __forceinline__ void load_lds16(const void* g, void* s) {
  // direct global->LDS DMA, 16B/lane; LDS dest is wave-uniform base + lane*16
  __builtin_amdgcn_global_load_lds((__attribute__((address_space(1))) unsigned int*)g,
                                   (__attribute__((address_space(3))) unsigned int*)s,
                                   16, 0, 0);
}

__device__ __forceinline__ float red_max16(float v) {
  v = fmaxf(v, __shfl_xor(v, 1));
  v = fmaxf(v, __shfl_xor(v, 2));
  v = fmaxf(v, __shfl_xor(v, 4));
  v = fmaxf(v, __shfl_xor(v, 8));
  return v;
}
__device__ __forceinline__ float red_sum16(float v) {
  v += __shfl_xor(v, 1);
  v += __shfl_xor(v, 2);
  v += __shfl_xor(v, 4);
  v += __shfl_xor(v, 8);
  return v;
}

// ---------------- fp32 -> bf16 convert (vectorized) ----------------
__global__ void tobf16(const float* __restrict__ in, bf16_t* __restrict__ out, int n4) {
  int i = blockIdx.x * 256 + threadIdx.x;
  if (i >= n4) return;
  float4 v = ((const float4*)in)[i];
  bf16x4v o;
  o[0] = (bf16_t)v.x; o[1] = (bf16_t)v.y; o[2] = (bf16_t)v.z; o[3] = (bf16_t)v.w;
  ((bf16x4v*)out)[i] = o;
}

// ---------------- GEMM: C[M,N] = A[M,K] @ B[N,K]^T + bias ----------------
// 128xBN tile, BK=32, 256 threads (4 waves 2x2). LDS 16B-unit XOR swizzle:
// unit (row,c) lives at row*4 + (c ^ ((row>>1)&3)) -> b128 reads are 2-way (free).
// EPI=0: QKV epilogue (scatter to q/k/vT bf16 layouts, q pre-scaled), BN=128
// EPI=1: proj epilogue (fp32 out), BN=64 for 2x grid
template <int EPI, int BN>
__global__ __launch_bounds__(256, 2) void gemm_bt(
    const bf16_t* __restrict__ A, const bf16_t* __restrict__ Bm,
    const float* __restrict__ bias,
    bf16_t* __restrict__ qb, bf16_t* __restrict__ kb, bf16_t* __restrict__ vtb,
    float* __restrict__ outf) {
  constexpr int NI = BN / 32;  // n-fragments per wave
  __shared__ __align__(16) bf16_t sA[128 * 32];
  __shared__ __align__(16) bf16_t sB[BN * 32];
  const int tid = threadIdx.x;
  const int w = tid >> 6, lane = tid & 63;
  const int wm = w >> 1, wn = w & 1;
  const int quad = lane >> 4, l15 = lane & 15;
  const int m0 = blockIdx.y * 128, n0 = blockIdx.x * BN;

  f32x4 acc[4][NI];
#pragma unroll
  for (int mi = 0; mi < 4; mi++)
#pragma unroll
    for (int ni = 0; ni < NI; ni++) acc[mi][ni] = (f32x4){0.f, 0.f, 0.f, 0.f};

  for (int kt = 0; kt < 1024; kt += 32) {
    __syncthreads();  // prior LDS reads done before restage
#pragma unroll
    for (int i = 0; i < 2; i++) {  // A: 512 units
      int ub = w * 128 + i * 64;
      int u = ub + lane;
      int r = u >> 2, c = (u & 3) ^ ((r >> 1) & 3);
      load_lds16(A + (size_t)(m0 + r) * 1024 + kt + c * 8, sA + ub * 8);
    }
#pragma unroll
    for (int i = 0; i < BN / 64; i++) {  // B: BN*4 units
      int ub = w * (BN / 64) * 64 + i * 64;
      int u = ub + lane;
      int r = u >> 2, c = (u & 3) ^ ((r >> 1) & 3);
      load_lds16(Bm + (size_t)(n0 + r) * 1024 + kt + c * 8, sB + ub * 8);
    }
    __syncthreads();  // drains vmcnt -> staged data visible
    bf16x8 af[4], bfr[NI];
#pragma unroll
    for (int mi = 0; mi < 4; mi++) {
      int r = wm * 64 + mi * 16 + l15;
      af[mi] = *(const bf16x8*)(sA + (r * 4 + (quad ^ ((r >> 1) & 3))) * 8);
    }
#pragma unroll
    for (int ni = 0; ni < NI; ni++) {
      int r = wn * (BN / 2) + ni * 16 + l15;
      bfr[ni] = *(const bf16x8*)(sB + (r * 4 + (quad ^ ((r >> 1) & 3))) * 8);
    }
#pragma unroll
    for (int mi = 0; mi < 4; mi++)
#pragma unroll
      for (int ni = 0; ni < NI; ni++)
        acc[mi][ni] = __builtin_amdgcn_mfma_f32_16x16x32_bf16(af[mi], bfr[ni], acc[mi][ni], 0, 0, 0);
  }

  // epilogue: C row = m0+wm*64+mi*16+quad*4+r, col = n0+wn*(BN/2)+ni*16+l15
#pragma unroll
  for (int mi = 0; mi < 4; mi++) {
#pragma unroll
    for (int ni = 0; ni < NI; ni++) {
      int n = n0 + wn * (BN / 2) + ni * 16 + l15;
      float bv = bias[n];
#pragma unroll
      for (int r = 0; r < 4; r++) {
        int m = m0 + wm * 64 + mi * 16 + quad * 4 + r;
        float v = acc[mi][ni][r] + bv;
        if (EPI == 0) {
          int t = n >> 10;           // 0=Q,1=K,2=V (uniform per block: 128 | 1024)
          int rr = n & 1023;
          int hh = rr >> 6, d = rr & 63;
          int bb = m >> 11, s = m & 2047;
          size_t bh = (size_t)(bb * H_ + hh);
          if (t == 0)
            qb[(bh * S_ + s) * HD_ + d] = (bf16_t)(v * QSCALE);
          else if (t == 1)
            kb[(bh * S_ + s) * HD_ + d] = (bf16_t)v;
          else
            vtb[(bh * HD_ + d) * S_ + s] = (bf16_t)v;  // V transposed for PV B-operand
        } else {
          outf[(size_t)m * 1024 + n] = v;
        }
      }
    }
  }
}

// ---------------- flash attention ----------------
// block = one (b,h,q-tile of 64). 4 waves; wave w owns q rows w*16..w*16+15
// for BOTH QK^T and PV -> online-softmax state (m,l,alpha) in registers.
// Q fragments are loop-invariant -> registers (no sQ). kv-tile = 128.
// sK/sV XOR-swizzled per 16B unit: (row,c) -> row*U + (c ^ (row&7)).
// P transits LDS (C-layout -> A-layout), stride 136 (272B: reads 2-way-free).
__global__ __launch_bounds__(256, 3) void attn(
    const bf16_t* __restrict__ qb, const bf16_t* __restrict__ kb,
    const bf16_t* __restrict__ vtb, bf16_t* __restrict__ ob) {
  __shared__ __align__(16) bf16_t sK[128 * 64];   // 16 KB, 8 units/row
  __shared__ __align__(16) bf16_t sV[64 * 128];   // 16 KB, [d][s], 16 units/row
  __shared__ __align__(16) bf16_t sP[64 * 136];   // 17 KB
  const int tid = threadIdx.x, w = tid >> 6, lane = tid & 63;
  const int quad = lane >> 4, l15 = lane & 15;
  const int qt = blockIdx.x, bh = blockIdx.y;
  const int b = bh >> 4, h = bh & 15;
  const size_t base = (size_t)bh * S_ * HD_;
  const size_t vbase = (size_t)bh * HD_ * S_;
  const int q0 = qt * 64;

  // Q fragments: loop-invariant, straight from global to registers
  bf16x8 aq[2];
#pragma unroll
  for (int kk = 0; kk < 2; kk++)
    aq[kk] = *(const bf16x8*)(qb + base + (size_t)(q0 + w * 16 + l15) * 64 + kk * 32 + quad * 8);

  f32x4 acc_o[4];
#pragma unroll
  for (int ni = 0; ni < 4; ni++) acc_o[ni] = (f32x4){0.f, 0.f, 0.f, 0.f};
  float m_r[4], l_r[4];
#pragma unroll
  for (int r = 0; r < 4; r++) { m_r[r] = -3.0e38f; l_r[r] = 0.f; }

  for (int j = 0; j < 16; j++) {
    const int kv0 = j * 128;
    __syncthreads();  // prev iter's K/V reads done
    // stage K [128 rows][8 units] and V^T [64 rows][16 units], swizzled
#pragma unroll
    for (int i = 0; i < 4; i++) {
      int ub = w * 256 + i * 64;
      int u = ub + lane;
      int rk = u >> 3, ck = (u & 7) ^ (rk & 7);
      load_lds16(kb + base + (size_t)(kv0 + rk) * 64 + ck * 8, sK + ub * 8);
      int rv = u >> 4, cv = (u & 15) ^ (rv & 7);
      load_lds16(vtb + vbase + (size_t)rv * S_ + kv0 + cv * 8, sV + ub * 8);
    }
    __syncthreads();

    // S = Q K^T : wave w -> rows w*16.., all 128 kv cols (8 n-tiles, 2 k-steps)
    f32x4 s_acc[8];
#pragma unroll
    for (int ni = 0; ni < 8; ni++) s_acc[ni] = (f32x4){0.f, 0.f, 0.f, 0.f};
#pragma unroll
    for (int kk = 0; kk < 2; kk++) {
#pragma unroll
      for (int ni = 0; ni < 8; ni++) {
        int r = ni * 16 + l15, c = kk * 4 + quad;
        bf16x8 bk = *(const bf16x8*)(sK + (r * 8 + (c ^ (r & 7))) * 8);
        s_acc[ni] = __builtin_amdgcn_mfma_f32_16x16x32_bf16(aq[kk], bk, s_acc[ni], 0, 0, 0);
      }
    }

    // online softmax (base-2; scale folded into Q). Row = w*16+quad*4+r.
    float alpha[4];
#pragma unroll
    for (int r = 0; r < 4; r++) {
      float mx = s_acc[0][r];
#pragma unroll
      for (int ni = 1; ni < 8; ni++) mx = fmaxf(mx, s_acc[ni][r]);
      mx = red_max16(mx);
      float mn = fmaxf(m_r[r], mx);
      alpha[r] = exp2f(m_r[r] - mn);  // first iter: exp2(-3e38)=0
      m_r[r] = mn;
      float rs = 0.f;
#pragma unroll
      for (int ni = 0; ni < 8; ni++) {
        float p = exp2f(s_acc[ni][r] - mn);
        rs += p;
        sP[(w * 16 + quad * 4 + r) * 136 + ni * 16 + l15] = (bf16_t)p;
      }
      rs = red_sum16(rs);
      l_r[r] = l_r[r] * alpha[r] + rs;
    }
    // no barrier: wave w writes AND reads only P rows w*16..w*16+15 (in-order LDS)

#pragma unroll
    for (int ni = 0; ni < 4; ni++)
#pragma unroll
      for (int r = 0; r < 4; r++) acc_o[ni][r] *= alpha[r];

    // O += P @ V : A = P rows (A-layout from LDS), B = V^T [d][s] (swizzled)
#pragma unroll
    for (int ks = 0; ks < 4; ks++) {
      bf16x8 ap = *(const bf16x8*)(sP + (w * 16 + l15) * 136 + ks * 32 + quad * 8);
#pragma unroll
      for (int ni = 0; ni < 4; ni++) {
        int r = ni * 16 + l15, c = ks * 4 + quad;
        bf16x8 bv = *(const bf16x8*)(sV + (r * 16 + (c ^ (r & 7))) * 8);
        acc_o[ni] = __builtin_amdgcn_mfma_f32_16x16x32_bf16(ap, bv, acc_o[ni], 0, 0, 0);
      }
    }
  }

  // epilogue: O row q, col d; write bf16 to [B,S,D] for proj GEMM
#pragma unroll
  for (int ni = 0; ni < 4; ni++)
#pragma unroll
    for (int r = 0; r < 4; r++) {
      int q = q0 + w * 16 + quad * 4 + r;
      int d = ni * 16 + l15;
      float v = acc_o[ni][r] / l_r[r];
      ob[((size_t)b * S_ + q) * D_ + h * HD_ + d] = (bf16_t)v;
    }
}

// ---------------- launcher ----------------
extern "C" void kernel_launch(void* const* d_in, const int* in_sizes, int n_in,
                              void* d_out, int out_size, void* d_ws, size_t ws_size,
                              hipStream_t stream) {
  const float* x = (const float*)d_in[0];        // [2,2048,1024]
  const float* w_qkv = (const float*)d_in[1];    // [3072,1024]
  const float* b_qkv = (const float*)d_in[2];    // [3072]
  const float* w_proj = (const float*)d_in[3];   // [1024,1024]
  const float* b_proj = (const float*)d_in[4];   // [1024]
  float* out = (float*)d_out;

  char* ws = (char*)d_ws;
  size_t off = 0;
  bf16_t* xb = (bf16_t*)(ws + off); off += (size_t)4096 * 1024 * 2;    // 8 MB
  bf16_t* wqkvb = (bf16_t*)(ws + off); off += (size_t)3072 * 1024 * 2; // 6 MB
  bf16_t* wpb = (bf16_t*)(ws + off); off += (size_t)1024 * 1024 * 2;   // 2 MB
  bf16_t* qb = (bf16_t*)(ws + off); off += (size_t)4096 * 1024 * 2;    // 8 MB [B,H,S,hd]
  bf16_t* kb = (bf16_t*)(ws + off); off += (size_t)4096 * 1024 * 2;    // 8 MB [B,H,S,hd]
  bf16_t* vtb = (bf16_t*)(ws + off); off += (size_t)4096 * 1024 * 2;   // 8 MB [B,H,hd,S]
  bf16_t* ob = xb;  // xb dead after QKV GEMM; reuse for attention output
  // total ws use: 41,943,040 B

  tobf16<<<4096, 256, 0, stream>>>(x, xb, 1048576);
  tobf16<<<3072, 256, 0, stream>>>(w_qkv, wqkvb, 786432);
  tobf16<<<1024, 256, 0, stream>>>(w_proj, wpb, 262144);
  gemm_bt<0, 128><<<dim3(24, 32), 256, 0, stream>>>(xb, wqkvb, b_qkv, qb, kb, vtb, nullptr);
  attn<<<dim3(32, 32), 256, 0, stream>>>(qb, kb, vtb, ob);
  gemm_bt<1, 64><<<dim3(16, 32), 256, 0, stream>>>(ob, wpb, b_proj, nullptr, nullptr, nullptr, out);
}